// Round 5
// baseline (680.931 us; speedup 1.0000x reference)
//
#include <hip/hip_runtime.h>
#include <hip/hip_bf16.h>

#define DI __device__ __forceinline__

typedef __attribute__((ext_vector_type(8))) __bf16 bf16x8;
typedef __attribute__((ext_vector_type(4))) float f32x4;
typedef __attribute__((ext_vector_type(2))) float f32x2;
typedef __attribute__((ext_vector_type(8))) unsigned short us8;
typedef __attribute__((ext_vector_type(4))) unsigned short us4;
typedef __attribute__((ext_vector_type(4))) int i32x4;

// ---- problem constants ----
constexpr int CBATCH = 8;
constexpr int HW = 64;          // H == W
constexpr int CDIM = 384;
constexpr int HEADS = 12;
constexpr int WS = 14;
constexpr int NTOK = 196;       // WS*WS
constexpr int NWIN = 200;       // 8 * 5 * 5
constexpr int MV = 39200;       // NWIN * NTOK
constexpr int MPAD = 39296;     // 307 * 128
constexpr int NQKV = 1152;
constexpr int HIDD = 1536;
constexpr int MMLP = 32768;     // 8 * 4096
constexpr int NBIAS = 12 * 13 * 13 * 4 * 16 * 4;  // tiled bias elements
constexpr float SCALE = 0.17677669529663687f;  // 32^-0.5

DI unsigned short f2bf(float f) { __bf16 b = (__bf16)f; return __builtin_bit_cast(unsigned short, b); }
DI bf16x8 ldfrag(const unsigned short* p) { return __builtin_bit_cast(bf16x8, *(const us8*)p); }
DI f32x4 mfma16(bf16x8 a, bf16x8 b, f32x4 c) {
  return __builtin_amdgcn_mfma_f32_16x16x32_bf16(a, b, c, 0, 0, 0);
}
DI void async16(const void* g, void* l) {
  __builtin_amdgcn_global_load_lds((const __attribute__((address_space(1))) void*)g,
                                   (__attribute__((address_space(3))) void*)l, 16, 0, 0);
}
// V-tile swizzled element address: Vt[32][256], conflict-free for both
// the transpose staging writes and the k-slice fragment reads.
DI int vt_addr(int d, int t) {
  return d * 256 + (((t & ~7) ^ ((d & 7) << 3) ^ (((d >> 3) & 3) << 5)) | (t & 7));
}

// ---------- small prep kernels ----------
__global__ __launch_bounds__(256) void k_cvt(const float* __restrict__ s,
                                             unsigned short* __restrict__ d, int n) {
  int i = blockIdx.x * 256 + threadIdx.x;
  if (i < n) d[i] = f2bf(s[i]);
}

// tiled f32 bias: bt[h][qt][kt][g][l15][r], matching the swapped-QK S^T fragment
__global__ __launch_bounds__(256) void k_bias2(const float* __restrict__ ab,
                                               const int* __restrict__ bidx,
                                               float* __restrict__ bt, int n_off) {
  int i = blockIdx.x * 256 + threadIdx.x;
  if (i >= NBIAS) return;
  int r = i & 3, l15 = (i >> 2) & 15, g = (i >> 6) & 3;
  int j = i >> 8;
  int kt = j % 13;
  int j2 = j / 13;
  int qt = j2 % 13;
  int h = j2 / 13;
  int q = qt * 16 + l15, k = kt * 16 + g * 4 + r;
  float v = 0.f;
  if (q < 196 && k < 196) v = ab[h * n_off + bidx[q * 196 + k]];
  bt[i] = v;
}

// ---------- LayerNorm (one wave per row, 6 f32/lane) ----------
template <int WIN>
__global__ __launch_bounds__(256) void k_ln(const float* __restrict__ src,
                                            const float* __restrict__ lw,
                                            const float* __restrict__ lb,
                                            unsigned short* __restrict__ dst) {
  const int row = blockIdx.x * 4 + (threadIdx.x >> 6);
  const int l = threadIdx.x & 63;
  const int c0 = l * 6;
  const float* p;
  bool valid;
  if (WIN) {
    int win = row / 196, t = row - win * 196;
    int b = win / 25, wi = win - b * 25;
    int wr = wi / 5, wc = wi - wr * 5;
    int hh = wr * 14 + t / 14, ww = wc * 14 + (t - (t / 14) * 14);
    valid = (row < MV) && (hh < HW) && (ww < HW);
    p = src + ((size_t)b * 4096 + hh * 64 + ww) * CDIM;
  } else {
    valid = true;
    p = src + (size_t)row * CDIM;
  }
  float v[6];
  if (valid) {
    f32x2 a = *(const f32x2*)(p + c0);
    f32x2 b2 = *(const f32x2*)(p + c0 + 2);
    f32x2 c2 = *(const f32x2*)(p + c0 + 4);
    v[0] = a.x; v[1] = a.y; v[2] = b2.x; v[3] = b2.y; v[4] = c2.x; v[5] = c2.y;
  } else {
#pragma unroll
    for (int k = 0; k < 6; ++k) v[k] = 0.f;
  }
  float s = 0.f, q = 0.f;
#pragma unroll
  for (int k = 0; k < 6; ++k) { s += v[k]; q += v[k] * v[k]; }
#pragma unroll
  for (int m = 1; m <= 32; m <<= 1) {
    s += __shfl_xor(s, m, 64);
    q += __shfl_xor(q, m, 64);
  }
  float mean = s * (1.0f / 384.0f);
  float var = q * (1.0f / 384.0f) - mean * mean;
  float rs = rsqrtf(var + 1e-5f);
#pragma unroll
  for (int k = 0; k < 6; ++k) {
    float y = (v[k] - mean) * rs * lw[c0 + k] + lb[c0 + k];
    dst[(size_t)row * CDIM + c0 + k] = f2bf(y);
  }
}

// ---------- depthwise 3x3 conv + BN ----------
__global__ __launch_bounds__(256) void k_conv(const float* __restrict__ x1,
                                              const float* __restrict__ cw,
                                              const float* __restrict__ bw,
                                              const float* __restrict__ bb,
                                              const float* __restrict__ bm,
                                              const float* __restrict__ bv,
                                              float* __restrict__ x2) {
  int idx = blockIdx.x * 256 + threadIdx.x;  // b*64*384 + x*384 + c
  int c = idx % 384;
  int x = (idx / 384) & 63;
  int b = idx / (384 * 64);
  const float* base = x1 + (size_t)b * 4096 * 384 + c;
  float w[9];
#pragma unroll
  for (int k = 0; k < 9; ++k) w[k] = cw[c * 9 + k];
  float sc = rsqrtf(bv[c] + 1e-5f) * bw[c];
  float sb = bb[c] - bm[c] * sc;
  float t0m = 0.f, t0c = 0.f, t0p = 0.f;
  float t1m, t1c, t1p, t2m, t2c, t2p;
  t1m = (x > 0) ? base[(x - 1) * 384] : 0.f;
  t1c = base[x * 384];
  t1p = (x < 63) ? base[(x + 1) * 384] : 0.f;
  for (int y = 0; y < 64; ++y) {
    if (y < 63) {
      int ro = (y + 1) * 64;
      t2m = (x > 0) ? base[(ro + x - 1) * 384] : 0.f;
      t2c = base[(ro + x) * 384];
      t2p = (x < 63) ? base[(ro + x + 1) * 384] : 0.f;
    } else { t2m = t2c = t2p = 0.f; }
    float o = w[0] * t0m + w[1] * t0c + w[2] * t0p +
              w[3] * t1m + w[4] * t1c + w[5] * t1p +
              w[6] * t2m + w[7] * t2c + w[8] * t2p;
    x2[((size_t)b * 4096 + y * 64 + x) * 384 + c] = o * sc + sb;
    t0m = t1m; t0c = t1c; t0p = t1p;
    t1m = t2m; t1c = t2c; t1p = t2p;
  }
}

// ---------- fused windowed attention: one block per (window, head) ----------
// Swapped QK^T (S^T = mfma(K,Q)), streaming softmax (no max-subtract; scores
// bounded), P kept entirely IN REGISTERS: the PV A-fragment is built by a
// cross-g lane exchange (4 ds_bpermute per kc). LDS holds only the swizzled
// V^T tile (16.4 KB) -> 4 blocks/CU at 4 waves/EU.
__global__ __launch_bounds__(256, 4) void k_attn(const unsigned short* __restrict__ qkv,
                                                 const float* __restrict__ bias_f,
                                                 unsigned short* __restrict__ aout) {
  __shared__ unsigned short Vt[32 * 256];
  const int bid = blockIdx.x;
  const int blk = (bid & 7) * 300 + (bid >> 3);  // XCD swizzle (2400 = 8*300)
  const int win = blk / 12, h = blk - win * 12;
  const int tid = threadIdx.x;
  const int w = tid >> 6, l = tid & 63;
  const int l15 = l & 15, g = l >> 4;
  const unsigned short* qb = qkv + (size_t)win * 196 * 1152 + h * 96;

  // stage V transposed + swizzled (rows t>=196 zeroed, t<224)
  for (int i = tid; i < 896; i += 256) {
    int t = i >> 2, d8 = (i & 3) << 3;
    us8 z = {0, 0, 0, 0, 0, 0, 0, 0};
    if (t < 196) z = *(const us8*)(qb + (size_t)t * 1152 + 64 + d8);
#pragma unroll
    for (int j = 0; j < 8; ++j) Vt[vt_addr(d8 + j, t)] = z[j];
  }
  __syncthreads();

  const float* bth = bias_f + (size_t)h * (13 * 13 * 4 * 16 * 4);
  // bpermute byte addresses for the cross-g P exchange:
  // quad1 src lane = l15 + 32*(g&1); quad2 src lane = +16
  const int pl1 = (l15 + ((l & 16) << 1)) << 2;
  const int pl2 = pl1 + 64;

  for (int qt = w; qt < 13; qt += 4) {
    // Q fragment from global (q pre-scaled by SCALE at the QKV epilogue)
    bf16x8 aq = ldfrag(qb + (size_t)(qt * 16 + l15) * 1152 + g * 8);
    float su = 0.f;
    us4 pk[13];
#pragma unroll
    for (int kt = 0; kt < 13; ++kt) {
      f32x4 zz = {0.f, 0.f, 0.f, 0.f};
      bf16x8 bk = ldfrag(qb + (size_t)(kt * 16 + l15) * 1152 + 32 + g * 8);
      f32x4 s = mfma16(bk, aq, zz);  // S^T: col=l15=q, row=g*4+r=k
      f32x4 bb = *(const f32x4*)(bth + (size_t)(((qt * 13 + kt) * 4 + g) * 16 + l15) * 4);
#pragma unroll
      for (int r = 0; r < 4; ++r) {
        float p = __expf(s[r] + bb[r]);
        if (kt == 12 && g != 0) p = 0.f;  // k = 192+g*4+r >= 196
        su += p;
        pk[kt][r] = f2bf(p);
      }
    }
    su += __shfl_xor(su, 16, 64);
    su += __shfl_xor(su, 32, 64);
    // PV: P stays in registers; A-fragment via cross-g bpermute exchange.
    // pa elem j holds P[q=l15][k=kc*32+g*8+j]; source kt=2kc+(g>>1),
    // quad1 from lane g'=2(g&1), quad2 from g'=2(g&1)+1.
    f32x4 o0 = {0.f, 0.f, 0.f, 0.f}, o1 = {0.f, 0.f, 0.f, 0.f};
#pragma unroll
    for (int kc = 0; kc < 7; ++kc) {
      us4 sel;
      if (kc < 6) {
        sel = (g & 2) ? pk[2 * kc + 1] : pk[2 * kc];
      } else {
        us4 z4 = {0, 0, 0, 0};
        sel = (g & 2) ? z4 : pk[12];  // k>=208 does not exist -> zero
      }
      int sx = (int)(((unsigned)sel[0]) | ((unsigned)sel[1] << 16));
      int sy = (int)(((unsigned)sel[2]) | ((unsigned)sel[3] << 16));
      i32x4 pw;
      pw[0] = __builtin_amdgcn_ds_bpermute(pl1, sx);
      pw[1] = __builtin_amdgcn_ds_bpermute(pl1, sy);
      pw[2] = __builtin_amdgcn_ds_bpermute(pl2, sx);
      pw[3] = __builtin_amdgcn_ds_bpermute(pl2, sy);
      bf16x8 pa = __builtin_bit_cast(bf16x8, pw);
      int t0 = kc * 32 + g * 8;
      bf16x8 b0 = ldfrag(&Vt[vt_addr(l15, t0)]);
      bf16x8 b1 = ldfrag(&Vt[vt_addr(16 + l15, t0)]);
      o0 = mfma16(pa, b0, o0);
      o1 = mfma16(pa, b1, o1);
    }
    float inv = 1.0f / su;
#pragma unroll
    for (int r = 0; r < 4; ++r) {
      int rw = qt * 16 + g * 4 + r;
      if (rw < 196) {
        size_t rb = ((size_t)win * 196 + rw) * 384 + h * 32;
        aout[rb + l15] = f2bf(o0[r] * inv);
        aout[rb + 16 + l15] = f2bf(o1[r] * inv);
      }
    }
  }
}

// ---------- bf16 GEMM, B^T weights, 128x128 tile, BK=64, templated epilogue ----
// MODE 0: +bias, scale q-cols by SCALE -> bf16 out (stride NQKV)
// MODE 1: +bias, window-reverse scatter, x1 = x + val (f32)
// MODE 2: +bias, exact GELU -> bf16 out (stride HIDD)
// MODE 3: +bias, out = auxr + val (f32, stride 384)
template <int MODE>
__global__ __launch_bounds__(256) void k_gemm(const unsigned short* __restrict__ A,
                                              const unsigned short* __restrict__ B,
                                              const float* __restrict__ bias,
                                              const float* __restrict__ auxr,
                                              float* __restrict__ auxw,
                                              unsigned short* __restrict__ outb,
                                              int K) {
  __shared__ unsigned short As[128 * 64];
  __shared__ unsigned short Bs[128 * 64];
  const int tid = threadIdx.x;
  const int w = tid >> 6, l = tid & 63;
  const int l15 = l & 15, g = l >> 4;
  const int wm = w >> 1, wn = w & 1;
  // bijective XCD-aware swizzle (m204) on the flat block index
  const int nwg = gridDim.x * gridDim.y;
  const int orig = blockIdx.y * gridDim.x + blockIdx.x;
  const int cq = nwg >> 3, cr = nwg & 7;
  const int xcd = orig & 7, cidx = orig >> 3;
  const int flat = (xcd < cr ? xcd * (cq + 1) : cr * (cq + 1) + (xcd - cr) * cq) + cidx;
  const int bx = flat % gridDim.x, by = flat / gridDim.x;
  const size_t arow0 = (size_t)bx * 128;
  const size_t brow0 = (size_t)by * 128;
  f32x4 acc[4][4] = {};
  for (int ks = 0; ks < K; ks += 64) {
    if (ks) __syncthreads();
#pragma unroll
    for (int it = 0; it < 4; ++it) {
      const int f = it * 256 + tid;
      const int r = f >> 3, c8 = (f & 7) << 3;
      const int lb = (it * 256 + w * 64) * 8;  // wave-uniform LDS base (elements)
      async16(A + (arow0 + r) * K + ks + c8, &As[lb]);
      async16(B + (brow0 + r) * K + ks + c8, &Bs[lb]);
    }
    __syncthreads();
#pragma unroll
    for (int kk = 0; kk < 2; ++kk) {
      bf16x8 af[4], bfr[4];
#pragma unroll
      for (int i = 0; i < 4; ++i)
        af[i] = ldfrag(&As[(wm * 64 + i * 16 + l15) * 64 + kk * 32 + g * 8]);
#pragma unroll
      for (int j = 0; j < 4; ++j)
        bfr[j] = ldfrag(&Bs[(wn * 64 + j * 16 + l15) * 64 + kk * 32 + g * 8]);
#pragma unroll
      for (int i = 0; i < 4; ++i)
#pragma unroll
        for (int j = 0; j < 4; ++j)
          acc[i][j] = mfma16(af[i], bfr[j], acc[i][j]);
    }
  }
  // epilogue
#pragma unroll
  for (int i = 0; i < 4; ++i) {
#pragma unroll
    for (int j = 0; j < 4; ++j) {
#pragma unroll
      for (int r = 0; r < 4; ++r) {
        const int row = (int)arow0 + wm * 64 + i * 16 + g * 4 + r;
        const int col = (int)brow0 + wn * 64 + j * 16 + l15;
        float v = acc[i][j][r] + bias[col];
        if (MODE == 0) {
          int ch = col % 96;
          float o = (ch < 32) ? v * SCALE : v;  // pre-scale q
          outb[(size_t)row * NQKV + col] = f2bf(o);
        } else if (MODE == 1) {
          if (row < MV) {
            int win = row / 196, t = row - win * 196;
            int b = win / 25, wi = win - b * 25;
            int wr = wi / 5, wc = wi - wr * 5;
            int hh = wr * 14 + t / 14, ww = wc * 14 + (t - (t / 14) * 14);
            if (hh < HW && ww < HW) {
              size_t di = ((size_t)b * 4096 + hh * 64 + ww) * 384 + col;
              auxw[di] = auxr[di] + v;
            }
          }
        } else if (MODE == 2) {
          float gl = 0.5f * v * (1.0f + erff(v * 0.7071067811865475f));
          outb[(size_t)row * HIDD + col] = f2bf(gl);
        } else {
          size_t di = (size_t)row * 384 + col;
          auxw[di] = auxr[di] + v;
        }
      }
    }
  }
}

// ---------- launcher ----------
extern "C" void kernel_launch(void* const* d_in, const int* in_sizes, int n_in,
                              void* d_out, int out_size, void* d_ws, size_t ws_size,
                              hipStream_t stream) {
  const float* x = (const float*)d_in[0];
  const float* ln_attn_w = (const float*)d_in[1];
  const float* ln_attn_b = (const float*)d_in[2];
  const float* qkv_w = (const float*)d_in[3];
  const float* qkv_b = (const float*)d_in[4];
  const float* proj_w = (const float*)d_in[5];
  const float* proj_b = (const float*)d_in[6];
  const float* attn_biases = (const float*)d_in[7];
  const float* conv_w = (const float*)d_in[8];
  const float* bn_w = (const float*)d_in[9];
  const float* bn_b = (const float*)d_in[10];
  const float* bn_mean = (const float*)d_in[11];
  const float* bn_var = (const float*)d_in[12];
  const float* ln_mlp_w = (const float*)d_in[13];
  const float* ln_mlp_b = (const float*)d_in[14];
  const float* fc1_w = (const float*)d_in[15];
  const float* fc1_b = (const float*)d_in[16];
  const float* fc2_w = (const float*)d_in[17];
  const float* fc2_b = (const float*)d_in[18];
  const int* bias_idx = (const int*)d_in[19];

  char* ws = (char*)d_ws;
  size_t off = 0;
  auto alloc = [&](size_t n) {
    void* p = ws + off;
    off = (off + n + 255) & ~(size_t)255;
    return p;
  };
  unsigned short* xn = (unsigned short*)alloc((size_t)MPAD * CDIM * 2);       // reused as xln
  unsigned short* qkv = (unsigned short*)alloc((size_t)MMLP * HIDD * 2);      // reused as h
  unsigned short* attn = (unsigned short*)alloc((size_t)MMLP * CDIM * 4);     // reused as x2 (f32)
  float* x1 = (float*)alloc((size_t)MMLP * CDIM * 4);
  unsigned short* wq = (unsigned short*)alloc((size_t)NQKV * CDIM * 2);
  unsigned short* wp = (unsigned short*)alloc((size_t)CDIM * CDIM * 2);
  unsigned short* w1 = (unsigned short*)alloc((size_t)HIDD * CDIM * 2);
  unsigned short* w2 = (unsigned short*)alloc((size_t)CDIM * HIDD * 2);
  float* bias_f = (float*)alloc((size_t)NBIAS * 4);
  unsigned short* hbuf = qkv;
  float* x2 = (float*)attn;
  unsigned short* xln = xn;
  int n_off = in_sizes[7] / HEADS;

  dim3 B256(256);
  k_cvt<<<dim3((NQKV * CDIM + 255) / 256), B256, 0, stream>>>(qkv_w, wq, NQKV * CDIM);
  k_cvt<<<dim3((CDIM * CDIM + 255) / 256), B256, 0, stream>>>(proj_w, wp, CDIM * CDIM);
  k_cvt<<<dim3((HIDD * CDIM + 255) / 256), B256, 0, stream>>>(fc1_w, w1, HIDD * CDIM);
  k_cvt<<<dim3((CDIM * HIDD + 255) / 256), B256, 0, stream>>>(fc2_w, w2, CDIM * HIDD);
  k_bias2<<<dim3((NBIAS + 255) / 256), B256, 0, stream>>>(attn_biases, bias_idx, bias_f, n_off);
  k_ln<1><<<dim3(MPAD / 4), B256, 0, stream>>>(x, ln_attn_w, ln_attn_b, xn);
  k_gemm<0><<<dim3(MPAD / 128, NQKV / 128), B256, 0, stream>>>(xn, wq, qkv_b, nullptr, nullptr, qkv, CDIM);
  k_attn<<<dim3(NWIN * HEADS), B256, 0, stream>>>(qkv, bias_f, attn);
  k_gemm<1><<<dim3(MPAD / 128, CDIM / 128), B256, 0, stream>>>(attn, wp, proj_b, x, x1, nullptr, CDIM);
  k_conv<<<dim3(CBATCH * HW * CDIM / 256), B256, 0, stream>>>(x1, conv_w, bn_w, bn_b, bn_mean, bn_var, x2);
  k_ln<0><<<dim3(MMLP / 4), B256, 0, stream>>>(x2, ln_mlp_w, ln_mlp_b, xln);
  k_gemm<2><<<dim3(MMLP / 128, HIDD / 128), B256, 0, stream>>>(xln, w1, fc1_b, nullptr, nullptr, hbuf, CDIM);
  k_gemm<3><<<dim3(MMLP / 128, CDIM / 128), B256, 0, stream>>>(hbuf, w2, fc2_b, x2, (float*)d_out, nullptr, HIDD);
}

// Round 6
// 560.236 us; speedup vs baseline: 1.2154x; 1.2154x over previous
//
#include <hip/hip_runtime.h>
#include <hip/hip_bf16.h>

#define DI __device__ __forceinline__

typedef __attribute__((ext_vector_type(8))) __bf16 bf16x8;
typedef __attribute__((ext_vector_type(4))) float f32x4;
typedef __attribute__((ext_vector_type(2))) float f32x2;
typedef __attribute__((ext_vector_type(8))) unsigned short us8;
typedef __attribute__((ext_vector_type(4))) unsigned short us4;

// ---- problem constants ----
constexpr int CBATCH = 8;
constexpr int HW = 64;          // H == W
constexpr int CDIM = 384;
constexpr int HEADS = 12;
constexpr int WS = 14;
constexpr int NTOK = 196;       // WS*WS
constexpr int NWIN = 200;       // 8 * 5 * 5
constexpr int MV = 39200;       // NWIN * NTOK
constexpr int MPAD = 39296;     // 307 * 128
constexpr int NQKV = 1152;
constexpr int HIDD = 1536;
constexpr int MMLP = 32768;     // 8 * 4096
constexpr int NBIAS = 12 * 13 * 13 * 4 * 16 * 4;  // tiled bias elements
constexpr int PLSTR = 228;      // P LDS row stride
constexpr float SCALE = 0.17677669529663687f;  // 32^-0.5

DI unsigned short f2bf(float f) { __bf16 b = (__bf16)f; return __builtin_bit_cast(unsigned short, b); }
DI float bf2f(unsigned short u) { unsigned x = (unsigned)u << 16; return __builtin_bit_cast(float, x); }
DI bf16x8 ldfrag(const unsigned short* p) { return __builtin_bit_cast(bf16x8, *(const us8*)p); }
DI f32x4 mfma16(bf16x8 a, bf16x8 b, f32x4 c) {
  return __builtin_amdgcn_mfma_f32_16x16x32_bf16(a, b, c, 0, 0, 0);
}
DI void async16(const void* g, void* l) {
  __builtin_amdgcn_global_load_lds((const __attribute__((address_space(1))) void*)g,
                                   (__attribute__((address_space(3))) void*)l, 16, 0, 0);
}
// V-tile swizzled element address: Vt[32][256], conflict-free for both
// the transpose staging writes and the k-slice fragment reads.
DI int vt_addr(int d, int t) {
  return d * 256 + (((t & ~7) ^ ((d & 7) << 3) ^ (((d >> 3) & 3) << 5)) | (t & 7));
}

// ---------- small prep kernels ----------
__global__ __launch_bounds__(256) void k_cvt(const float* __restrict__ s,
                                             unsigned short* __restrict__ d, int n) {
  int i = blockIdx.x * 256 + threadIdx.x;
  if (i < n) d[i] = f2bf(s[i]);
}

// tiled bf16 bias: bt[h][qt][kt][g][l15][r], matching the swapped-QK S^T fragment
__global__ __launch_bounds__(256) void k_bias2(const float* __restrict__ ab,
                                               const int* __restrict__ bidx,
                                               unsigned short* __restrict__ bt, int n_off) {
  int i = blockIdx.x * 256 + threadIdx.x;
  if (i >= NBIAS) return;
  int r = i & 3, l15 = (i >> 2) & 15, g = (i >> 6) & 3;
  int j = i >> 8;
  int kt = j % 13;
  int j2 = j / 13;
  int qt = j2 % 13;
  int h = j2 / 13;
  int q = qt * 16 + l15, k = kt * 16 + g * 4 + r;
  float v = 0.f;
  if (q < 196 && k < 196) v = ab[h * n_off + bidx[q * 196 + k]];
  bt[i] = f2bf(v);
}

// ---------- LayerNorm (one wave per row, 6 f32/lane) ----------
template <int WIN>
__global__ __launch_bounds__(256) void k_ln(const float* __restrict__ src,
                                            const float* __restrict__ lw,
                                            const float* __restrict__ lb,
                                            unsigned short* __restrict__ dst) {
  const int row = blockIdx.x * 4 + (threadIdx.x >> 6);
  const int l = threadIdx.x & 63;
  const int c0 = l * 6;
  const float* p;
  bool valid;
  if (WIN) {
    int win = row / 196, t = row - win * 196;
    int b = win / 25, wi = win - b * 25;
    int wr = wi / 5, wc = wi - wr * 5;
    int hh = wr * 14 + t / 14, ww = wc * 14 + (t - (t / 14) * 14);
    valid = (row < MV) && (hh < HW) && (ww < HW);
    p = src + ((size_t)b * 4096 + hh * 64 + ww) * CDIM;
  } else {
    valid = true;
    p = src + (size_t)row * CDIM;
  }
  float v[6];
  if (valid) {
    f32x2 a = *(const f32x2*)(p + c0);
    f32x2 b2 = *(const f32x2*)(p + c0 + 2);
    f32x2 c2 = *(const f32x2*)(p + c0 + 4);
    v[0] = a.x; v[1] = a.y; v[2] = b2.x; v[3] = b2.y; v[4] = c2.x; v[5] = c2.y;
  } else {
#pragma unroll
    for (int k = 0; k < 6; ++k) v[k] = 0.f;
  }
  float s = 0.f, q = 0.f;
#pragma unroll
  for (int k = 0; k < 6; ++k) { s += v[k]; q += v[k] * v[k]; }
#pragma unroll
  for (int m = 1; m <= 32; m <<= 1) {
    s += __shfl_xor(s, m, 64);
    q += __shfl_xor(q, m, 64);
  }
  float mean = s * (1.0f / 384.0f);
  float var = q * (1.0f / 384.0f) - mean * mean;
  float rs = rsqrtf(var + 1e-5f);
#pragma unroll
  for (int k = 0; k < 6; ++k) {
    float y = (v[k] - mean) * rs * lw[c0 + k] + lb[c0 + k];
    dst[(size_t)row * CDIM + c0 + k] = f2bf(y);
  }
}

// ---------- depthwise 3x3 conv + BN ----------
__global__ __launch_bounds__(256) void k_conv(const float* __restrict__ x1,
                                              const float* __restrict__ cw,
                                              const float* __restrict__ bw,
                                              const float* __restrict__ bb,
                                              const float* __restrict__ bm,
                                              const float* __restrict__ bv,
                                              float* __restrict__ x2) {
  int idx = blockIdx.x * 256 + threadIdx.x;  // b*64*384 + x*384 + c
  int c = idx % 384;
  int x = (idx / 384) & 63;
  int b = idx / (384 * 64);
  const float* base = x1 + (size_t)b * 4096 * 384 + c;
  float w[9];
#pragma unroll
  for (int k = 0; k < 9; ++k) w[k] = cw[c * 9 + k];
  float sc = rsqrtf(bv[c] + 1e-5f) * bw[c];
  float sb = bb[c] - bm[c] * sc;
  float t0m = 0.f, t0c = 0.f, t0p = 0.f;
  float t1m, t1c, t1p, t2m, t2c, t2p;
  t1m = (x > 0) ? base[(x - 1) * 384] : 0.f;
  t1c = base[x * 384];
  t1p = (x < 63) ? base[(x + 1) * 384] : 0.f;
  for (int y = 0; y < 64; ++y) {
    if (y < 63) {
      int ro = (y + 1) * 64;
      t2m = (x > 0) ? base[(ro + x - 1) * 384] : 0.f;
      t2c = base[(ro + x) * 384];
      t2p = (x < 63) ? base[(ro + x + 1) * 384] : 0.f;
    } else { t2m = t2c = t2p = 0.f; }
    float o = w[0] * t0m + w[1] * t0c + w[2] * t0p +
              w[3] * t1m + w[4] * t1c + w[5] * t1p +
              w[6] * t2m + w[7] * t2c + w[8] * t2p;
    x2[((size_t)b * 4096 + y * 64 + x) * 384 + c] = o * sc + sb;
    t0m = t1m; t0c = t1c; t0p = t1p;
    t1m = t2m; t1c = t2c; t1p = t2p;
  }
}

// ---------- fused windowed attention: one block per (window, head) ----------
// Swapped QK^T (S^T = mfma(K,Q)), streaming softmax (no max-subtract; scores
// bounded), LDS-P transfer (round-4 verified path). NEW: K fragments are
// hoisted into registers ONCE PER BLOCK (K invariant across qt iters) and the
// 13 bias vectors preloaded per iter -> the per-iter serial L2 latency chain
// collapses into one burst. LDS 45.5 KB -> 3 blocks/CU; VGPR cap 168 (LDS is
// the occupancy limiter, so no spill risk).
__global__ __launch_bounds__(256, 3) void k_attn(const unsigned short* __restrict__ qkv,
                                                 const unsigned short* __restrict__ bias_t,
                                                 unsigned short* __restrict__ aout) {
  __shared__ unsigned short Vt[32 * 256];
  __shared__ unsigned short Pl[4][16 * PLSTR];
  const int bid = blockIdx.x;
  const int blk = (bid & 7) * 300 + (bid >> 3);  // XCD swizzle (2400 = 8*300)
  const int win = blk / 12, h = blk - win * 12;
  const int tid = threadIdx.x;
  const int w = tid >> 6, l = tid & 63;
  const int l15 = l & 15, g = l >> 4;
  const unsigned short* qb = qkv + (size_t)win * 196 * 1152 + h * 96;

  // stage V transposed + swizzled (rows t>=196 zeroed, t<224)
  for (int i = tid; i < 896; i += 256) {
    int t = i >> 2, d8 = (i & 3) << 3;
    us8 z = {0, 0, 0, 0, 0, 0, 0, 0};
    if (t < 196) z = *(const us8*)(qb + (size_t)t * 1152 + 64 + d8);
#pragma unroll
    for (int j = 0; j < 8; ++j) Vt[vt_addr(d8 + j, t)] = z[j];
  }
  // zero P pad cols 208..227 (per wave, persists across iterations)
  for (int z = l; z < 16 * 20; z += 64) {
    int rr = z / 20, cc = 208 + (z - rr * 20);
    Pl[w][rr * PLSTR + cc] = 0;
  }
  __syncthreads();

  // hoist all 13 K fragments into registers (invariant across qt)
  bf16x8 bkv[13];
#pragma unroll
  for (int kt = 0; kt < 13; ++kt)
    bkv[kt] = ldfrag(qb + (size_t)(kt * 16 + l15) * 1152 + 32 + g * 8);

  const unsigned short* bth = bias_t + (size_t)h * (13 * 13 * 4 * 16 * 4);
  unsigned short* plw = &Pl[w][0];
  for (int qt = w; qt < 13; qt += 4) {
    // Q fragment + all 13 bias vectors issued as one burst
    bf16x8 aq = ldfrag(qb + (size_t)(qt * 16 + l15) * 1152 + g * 8);
    us4 bv[13];
#pragma unroll
    for (int kt = 0; kt < 13; ++kt)
      bv[kt] = *(const us4*)(bth + (size_t)(((qt * 13 + kt) * 4 + g) * 16 + l15) * 4);

    float su = 0.f;
#pragma unroll
    for (int kt = 0; kt < 13; ++kt) {
      f32x4 zz = {0.f, 0.f, 0.f, 0.f};
      f32x4 s = mfma16(bkv[kt], aq, zz);  // S^T: col=l15=q, row=g*4+r=k
      us4 pk;
#pragma unroll
      for (int r = 0; r < 4; ++r) {
        float p = __expf(s[r] + bf2f(bv[kt][r]));
        if (kt == 12 && g != 0) p = 0.f;  // k = 192+g*4+r >= 196
        su += p;
        pk[r] = f2bf(p);
      }
      *(us4*)(plw + l15 * PLSTR + kt * 16 + g * 4) = pk;
    }
    su += __shfl_xor(su, 16, 64);
    su += __shfl_xor(su, 32, 64);
    asm volatile("s_waitcnt lgkmcnt(0)" ::: "memory");
    __builtin_amdgcn_sched_barrier(0);
    // PV (P unnormalized)
    f32x4 o0 = {0.f, 0.f, 0.f, 0.f}, o1 = {0.f, 0.f, 0.f, 0.f};
#pragma unroll
    for (int kc = 0; kc < 7; ++kc) {
      int t0 = kc * 32 + g * 8;
      bf16x8 pa = ldfrag(plw + l15 * PLSTR + t0);
      bf16x8 b0 = ldfrag(&Vt[vt_addr(l15, t0)]);
      bf16x8 b1 = ldfrag(&Vt[vt_addr(16 + l15, t0)]);
      o0 = mfma16(pa, b0, o0);
      o1 = mfma16(pa, b1, o1);
    }
    float inv = 1.0f / su;
#pragma unroll
    for (int r = 0; r < 4; ++r) {
      int rw = qt * 16 + g * 4 + r;
      if (rw < 196) {
        size_t rb = ((size_t)win * 196 + rw) * 384 + h * 32;
        aout[rb + l15] = f2bf(o0[r] * inv);
        aout[rb + 16 + l15] = f2bf(o1[r] * inv);
      }
    }
  }
}

// ---------- bf16 GEMM, B^T weights, 128x128 tile, BK=64, templated epilogue ----
// MODE 0: +bias, scale q-cols by SCALE -> bf16 out (stride NQKV)
// MODE 1: +bias, window-reverse scatter, x1 = x + val (f32)
// MODE 2: +bias, exact GELU -> bf16 out (stride HIDD)
// MODE 3: +bias, out = auxr + val (f32, stride 384)
template <int MODE, int K>
__global__ __launch_bounds__(256) void k_gemm(const unsigned short* __restrict__ A,
                                              const unsigned short* __restrict__ B,
                                              const float* __restrict__ bias,
                                              const float* __restrict__ auxr,
                                              float* __restrict__ auxw,
                                              unsigned short* __restrict__ outb) {
  __shared__ unsigned short As[128 * 64];
  __shared__ unsigned short Bs[128 * 64];
  const int tid = threadIdx.x;
  const int w = tid >> 6, l = tid & 63;
  const int l15 = l & 15, g = l >> 4;
  const int wm = w >> 1, wn = w & 1;
  // bijective XCD-aware swizzle (m204) on the flat block index
  const int nwg = gridDim.x * gridDim.y;
  const int orig = blockIdx.y * gridDim.x + blockIdx.x;
  const int cq = nwg >> 3, cr = nwg & 7;
  const int xcd = orig & 7, cidx = orig >> 3;
  const int flat = (xcd < cr ? xcd * (cq + 1) : cr * (cq + 1) + (xcd - cr) * cq) + cidx;
  const int bx = flat % gridDim.x, by = flat / gridDim.x;
  const size_t arow0 = (size_t)bx * 128;
  const size_t brow0 = (size_t)by * 128;
  f32x4 acc[4][4] = {};
  for (int ks = 0; ks < K; ks += 64) {
    if (ks) __syncthreads();
#pragma unroll
    for (int it = 0; it < 4; ++it) {
      const int f = it * 256 + tid;
      const int r = f >> 3, c8 = (f & 7) << 3;
      const int lb = (it * 256 + w * 64) * 8;  // wave-uniform LDS base (elements)
      async16(A + (arow0 + r) * K + ks + c8, &As[lb]);
      async16(B + (brow0 + r) * K + ks + c8, &Bs[lb]);
    }
    __syncthreads();
#pragma unroll
    for (int kk = 0; kk < 2; ++kk) {
      bf16x8 af[4], bfr[4];
#pragma unroll
      for (int i = 0; i < 4; ++i)
        af[i] = ldfrag(&As[(wm * 64 + i * 16 + l15) * 64 + kk * 32 + g * 8]);
#pragma unroll
      for (int j = 0; j < 4; ++j)
        bfr[j] = ldfrag(&Bs[(wn * 64 + j * 16 + l15) * 64 + kk * 32 + g * 8]);
#pragma unroll
      for (int i = 0; i < 4; ++i)
#pragma unroll
        for (int j = 0; j < 4; ++j)
          acc[i][j] = mfma16(af[i], bfr[j], acc[i][j]);
    }
  }
  // epilogue
#pragma unroll
  for (int i = 0; i < 4; ++i) {
#pragma unroll
    for (int j = 0; j < 4; ++j) {
#pragma unroll
      for (int r = 0; r < 4; ++r) {
        const int row = (int)arow0 + wm * 64 + i * 16 + g * 4 + r;
        const int col = (int)brow0 + wn * 64 + j * 16 + l15;
        float v = acc[i][j][r] + bias[col];
        if (MODE == 0) {
          int ch = col % 96;
          float o = (ch < 32) ? v * SCALE : v;  // pre-scale q
          outb[(size_t)row * NQKV + col] = f2bf(o);
        } else if (MODE == 1) {
          if (row < MV) {
            int win = row / 196, t = row - win * 196;
            int b = win / 25, wi = win - b * 25;
            int wr = wi / 5, wc = wi - wr * 5;
            int hh = wr * 14 + t / 14, ww = wc * 14 + (t - (t / 14) * 14);
            if (hh < HW && ww < HW) {
              size_t di = ((size_t)b * 4096 + hh * 64 + ww) * 384 + col;
              auxw[di] = auxr[di] + v;
            }
          }
        } else if (MODE == 2) {
          float gl = 0.5f * v * (1.0f + erff(v * 0.7071067811865475f));
          outb[(size_t)row * HIDD + col] = f2bf(gl);
        } else {
          size_t di = (size_t)row * 384 + col;
          auxw[di] = auxr[di] + v;
        }
      }
    }
  }
}

// ---------- launcher ----------
extern "C" void kernel_launch(void* const* d_in, const int* in_sizes, int n_in,
                              void* d_out, int out_size, void* d_ws, size_t ws_size,
                              hipStream_t stream) {
  const float* x = (const float*)d_in[0];
  const float* ln_attn_w = (const float*)d_in[1];
  const float* ln_attn_b = (const float*)d_in[2];
  const float* qkv_w = (const float*)d_in[3];
  const float* qkv_b = (const float*)d_in[4];
  const float* proj_w = (const float*)d_in[5];
  const float* proj_b = (const float*)d_in[6];
  const float* attn_biases = (const float*)d_in[7];
  const float* conv_w = (const float*)d_in[8];
  const float* bn_w = (const float*)d_in[9];
  const float* bn_b = (const float*)d_in[10];
  const float* bn_mean = (const float*)d_in[11];
  const float* bn_var = (const float*)d_in[12];
  const float* ln_mlp_w = (const float*)d_in[13];
  const float* ln_mlp_b = (const float*)d_in[14];
  const float* fc1_w = (const float*)d_in[15];
  const float* fc1_b = (const float*)d_in[16];
  const float* fc2_w = (const float*)d_in[17];
  const float* fc2_b = (const float*)d_in[18];
  const int* bias_idx = (const int*)d_in[19];

  char* ws = (char*)d_ws;
  size_t off = 0;
  auto alloc = [&](size_t n) {
    void* p = ws + off;
    off = (off + n + 255) & ~(size_t)255;
    return p;
  };
  unsigned short* xn = (unsigned short*)alloc((size_t)MPAD * CDIM * 2);       // reused as xln
  unsigned short* qkv = (unsigned short*)alloc((size_t)MMLP * HIDD * 2);      // reused as h
  unsigned short* attn = (unsigned short*)alloc((size_t)MMLP * CDIM * 4);     // reused as x2 (f32)
  float* x1 = (float*)alloc((size_t)MMLP * CDIM * 4);
  unsigned short* wq = (unsigned short*)alloc((size_t)NQKV * CDIM * 2);
  unsigned short* wp = (unsigned short*)alloc((size_t)CDIM * CDIM * 2);
  unsigned short* w1 = (unsigned short*)alloc((size_t)HIDD * CDIM * 2);
  unsigned short* w2 = (unsigned short*)alloc((size_t)CDIM * HIDD * 2);
  unsigned short* bias_t = (unsigned short*)alloc((size_t)NBIAS * 2);
  unsigned short* hbuf = qkv;
  float* x2 = (float*)attn;
  unsigned short* xln = xn;
  int n_off = in_sizes[7] / HEADS;

  dim3 B256(256);
  k_cvt<<<dim3((NQKV * CDIM + 255) / 256), B256, 0, stream>>>(qkv_w, wq, NQKV * CDIM);
  k_cvt<<<dim3((CDIM * CDIM + 255) / 256), B256, 0, stream>>>(proj_w, wp, CDIM * CDIM);
  k_cvt<<<dim3((HIDD * CDIM + 255) / 256), B256, 0, stream>>>(fc1_w, w1, HIDD * CDIM);
  k_cvt<<<dim3((CDIM * HIDD + 255) / 256), B256, 0, stream>>>(fc2_w, w2, CDIM * HIDD);
  k_bias2<<<dim3((NBIAS + 255) / 256), B256, 0, stream>>>(attn_biases, bias_idx, bias_t, n_off);
  k_ln<1><<<dim3(MPAD / 4), B256, 0, stream>>>(x, ln_attn_w, ln_attn_b, xn);
  k_gemm<0, CDIM><<<dim3(MPAD / 128, NQKV / 128), B256, 0, stream>>>(xn, wq, qkv_b, nullptr, nullptr, qkv);
  k_attn<<<dim3(NWIN * HEADS), B256, 0, stream>>>(qkv, bias_t, attn);
  k_gemm<1, CDIM><<<dim3(MPAD / 128, CDIM / 128), B256, 0, stream>>>(attn, wp, proj_b, x, x1, nullptr);
  k_conv<<<dim3(CBATCH * HW * CDIM / 256), B256, 0, stream>>>(x1, conv_w, bn_w, bn_b, bn_mean, bn_var, x2);
  k_ln<0><<<dim3(MMLP / 4), B256, 0, stream>>>(x2, ln_mlp_w, ln_mlp_b, xln);
  k_gemm<2, CDIM><<<dim3(MMLP / 128, HIDD / 128), B256, 0, stream>>>(xln, w1, fc1_b, nullptr, nullptr, hbuf);
  k_gemm<3, HIDD><<<dim3(MMLP / 128, CDIM / 128), B256, 0, stream>>>(hbuf, w2, fc2_b, x2, (float*)d_out, nullptr);
}

// Round 7
// 557.455 us; speedup vs baseline: 1.2215x; 1.0050x over previous
//
#include <hip/hip_runtime.h>
#include <hip/hip_bf16.h>

#define DI __device__ __forceinline__

typedef __attribute__((ext_vector_type(8))) __bf16 bf16x8;
typedef __attribute__((ext_vector_type(4))) float f32x4;
typedef __attribute__((ext_vector_type(2))) float f32x2;
typedef __attribute__((ext_vector_type(8))) unsigned short us8;
typedef __attribute__((ext_vector_type(4))) unsigned short us4;

// ---- problem constants ----
constexpr int CBATCH = 8;
constexpr int HW = 64;          // H == W
constexpr int CDIM = 384;
constexpr int HEADS = 12;
constexpr int WS = 14;
constexpr int NTOK = 196;       // WS*WS
constexpr int NWIN = 200;       // 8 * 5 * 5
constexpr int MV = 39200;       // NWIN * NTOK
constexpr int MPAD = 39296;     // 307 * 128
constexpr int NQKV = 1152;
constexpr int HIDD = 1536;
constexpr int MMLP = 32768;     // 8 * 4096
constexpr int NBIAS = 12 * 13 * 13 * 4 * 16 * 4;  // tiled bias elements
constexpr int PLSTR = 228;      // P LDS row stride
constexpr float SCALE = 0.17677669529663687f;  // 32^-0.5

DI unsigned short f2bf(float f) { __bf16 b = (__bf16)f; return __builtin_bit_cast(unsigned short, b); }
DI float bf2f(unsigned short u) { unsigned x = (unsigned)u << 16; return __builtin_bit_cast(float, x); }
DI bf16x8 ldfrag(const unsigned short* p) { return __builtin_bit_cast(bf16x8, *(const us8*)p); }
DI f32x4 mfma16(bf16x8 a, bf16x8 b, f32x4 c) {
  return __builtin_amdgcn_mfma_f32_16x16x32_bf16(a, b, c, 0, 0, 0);
}
DI void async16(const void* g, void* l) {
  __builtin_amdgcn_global_load_lds((const __attribute__((address_space(1))) void*)g,
                                   (__attribute__((address_space(3))) void*)l, 16, 0, 0);
}
// V-tile swizzled element address: Vt[32][256], conflict-free for both
// the transpose staging writes and the k-slice fragment reads.
DI int vt_addr(int d, int t) {
  return d * 256 + (((t & ~7) ^ ((d & 7) << 3) ^ (((d >> 3) & 3) << 5)) | (t & 7));
}

// ---------- small prep kernels ----------
__global__ __launch_bounds__(256) void k_cvt(const float* __restrict__ s,
                                             unsigned short* __restrict__ d, int n) {
  int i = blockIdx.x * 256 + threadIdx.x;
  if (i < n) d[i] = f2bf(s[i]);
}

// tiled bf16 bias: bt[h][qt][kt][g][l15][r], matching the swapped-QK S^T fragment
__global__ __launch_bounds__(256) void k_bias2(const float* __restrict__ ab,
                                               const int* __restrict__ bidx,
                                               unsigned short* __restrict__ bt, int n_off) {
  int i = blockIdx.x * 256 + threadIdx.x;
  if (i >= NBIAS) return;
  int r = i & 3, l15 = (i >> 2) & 15, g = (i >> 6) & 3;
  int j = i >> 8;
  int kt = j % 13;
  int j2 = j / 13;
  int qt = j2 % 13;
  int h = j2 / 13;
  int q = qt * 16 + l15, k = kt * 16 + g * 4 + r;
  float v = 0.f;
  if (q < 196 && k < 196) v = ab[h * n_off + bidx[q * 196 + k]];
  bt[i] = f2bf(v);
}

// ---------- LayerNorm (one wave per row, 6 f32/lane) ----------
template <int WIN>
__global__ __launch_bounds__(256) void k_ln(const float* __restrict__ src,
                                            const float* __restrict__ lw,
                                            const float* __restrict__ lb,
                                            unsigned short* __restrict__ dst) {
  const int row = blockIdx.x * 4 + (threadIdx.x >> 6);
  const int l = threadIdx.x & 63;
  const int c0 = l * 6;
  const float* p;
  bool valid;
  if (WIN) {
    int win = row / 196, t = row - win * 196;
    int b = win / 25, wi = win - b * 25;
    int wr = wi / 5, wc = wi - wr * 5;
    int hh = wr * 14 + t / 14, ww = wc * 14 + (t - (t / 14) * 14);
    valid = (row < MV) && (hh < HW) && (ww < HW);
    p = src + ((size_t)b * 4096 + hh * 64 + ww) * CDIM;
  } else {
    valid = true;
    p = src + (size_t)row * CDIM;
  }
  float v[6];
  if (valid) {
    f32x2 a = *(const f32x2*)(p + c0);
    f32x2 b2 = *(const f32x2*)(p + c0 + 2);
    f32x2 c2 = *(const f32x2*)(p + c0 + 4);
    v[0] = a.x; v[1] = a.y; v[2] = b2.x; v[3] = b2.y; v[4] = c2.x; v[5] = c2.y;
  } else {
#pragma unroll
    for (int k = 0; k < 6; ++k) v[k] = 0.f;
  }
  float s = 0.f, q = 0.f;
#pragma unroll
  for (int k = 0; k < 6; ++k) { s += v[k]; q += v[k] * v[k]; }
#pragma unroll
  for (int m = 1; m <= 32; m <<= 1) {
    s += __shfl_xor(s, m, 64);
    q += __shfl_xor(q, m, 64);
  }
  float mean = s * (1.0f / 384.0f);
  float var = q * (1.0f / 384.0f) - mean * mean;
  float rs = rsqrtf(var + 1e-5f);
#pragma unroll
  for (int k = 0; k < 6; ++k) {
    float y = (v[k] - mean) * rs * lw[c0 + k] + lb[c0 + k];
    dst[(size_t)row * CDIM + c0 + k] = f2bf(y);
  }
}

// ---------- depthwise 3x3 conv + BN ----------
__global__ __launch_bounds__(256) void k_conv(const float* __restrict__ x1,
                                              const float* __restrict__ cw,
                                              const float* __restrict__ bw,
                                              const float* __restrict__ bb,
                                              const float* __restrict__ bm,
                                              const float* __restrict__ bv,
                                              float* __restrict__ x2) {
  int idx = blockIdx.x * 256 + threadIdx.x;  // b*64*384 + x*384 + c
  int c = idx % 384;
  int x = (idx / 384) & 63;
  int b = idx / (384 * 64);
  const float* base = x1 + (size_t)b * 4096 * 384 + c;
  float w[9];
#pragma unroll
  for (int k = 0; k < 9; ++k) w[k] = cw[c * 9 + k];
  float sc = rsqrtf(bv[c] + 1e-5f) * bw[c];
  float sb = bb[c] - bm[c] * sc;
  float t0m = 0.f, t0c = 0.f, t0p = 0.f;
  float t1m, t1c, t1p, t2m, t2c, t2p;
  t1m = (x > 0) ? base[(x - 1) * 384] : 0.f;
  t1c = base[x * 384];
  t1p = (x < 63) ? base[(x + 1) * 384] : 0.f;
  for (int y = 0; y < 64; ++y) {
    if (y < 63) {
      int ro = (y + 1) * 64;
      t2m = (x > 0) ? base[(ro + x - 1) * 384] : 0.f;
      t2c = base[(ro + x) * 384];
      t2p = (x < 63) ? base[(ro + x + 1) * 384] : 0.f;
    } else { t2m = t2c = t2p = 0.f; }
    float o = w[0] * t0m + w[1] * t0c + w[2] * t0p +
              w[3] * t1m + w[4] * t1c + w[5] * t1p +
              w[6] * t2m + w[7] * t2c + w[8] * t2p;
    x2[((size_t)b * 4096 + y * 64 + x) * 384 + c] = o * sc + sb;
    t0m = t1m; t0c = t1c; t0p = t1p;
    t1m = t2m; t1c = t2c; t1p = t2p;
  }
}

// ---------- fused windowed attention: one block per (window, head) ----------
// Swapped QK^T (S^T = mfma(K,Q)), streaming softmax, LDS-P transfer,
// K fragments hoisted per block, bias burst-preloaded per iter.
__global__ __launch_bounds__(256, 3) void k_attn(const unsigned short* __restrict__ qkv,
                                                 const unsigned short* __restrict__ bias_t,
                                                 unsigned short* __restrict__ aout) {
  __shared__ unsigned short Vt[32 * 256];
  __shared__ unsigned short Pl[4][16 * PLSTR];
  const int bid = blockIdx.x;
  const int blk = (bid & 7) * 300 + (bid >> 3);  // XCD swizzle (2400 = 8*300)
  const int win = blk / 12, h = blk - win * 12;
  const int tid = threadIdx.x;
  const int w = tid >> 6, l = tid & 63;
  const int l15 = l & 15, g = l >> 4;
  const unsigned short* qb = qkv + (size_t)win * 196 * 1152 + h * 96;

  // stage V transposed + swizzled (rows t>=196 zeroed, t<224)
  for (int i = tid; i < 896; i += 256) {
    int t = i >> 2, d8 = (i & 3) << 3;
    us8 z = {0, 0, 0, 0, 0, 0, 0, 0};
    if (t < 196) z = *(const us8*)(qb + (size_t)t * 1152 + 64 + d8);
#pragma unroll
    for (int j = 0; j < 8; ++j) Vt[vt_addr(d8 + j, t)] = z[j];
  }
  // zero P pad cols 208..227 (per wave, persists across iterations)
  for (int z = l; z < 16 * 20; z += 64) {
    int rr = z / 20, cc = 208 + (z - rr * 20);
    Pl[w][rr * PLSTR + cc] = 0;
  }
  __syncthreads();

  // hoist all 13 K fragments into registers (invariant across qt)
  bf16x8 bkv[13];
#pragma unroll
  for (int kt = 0; kt < 13; ++kt)
    bkv[kt] = ldfrag(qb + (size_t)(kt * 16 + l15) * 1152 + 32 + g * 8);

  const unsigned short* bth = bias_t + (size_t)h * (13 * 13 * 4 * 16 * 4);
  unsigned short* plw = &Pl[w][0];
  for (int qt = w; qt < 13; qt += 4) {
    // Q fragment + all 13 bias vectors issued as one burst
    bf16x8 aq = ldfrag(qb + (size_t)(qt * 16 + l15) * 1152 + g * 8);
    us4 bv[13];
#pragma unroll
    for (int kt = 0; kt < 13; ++kt)
      bv[kt] = *(const us4*)(bth + (size_t)(((qt * 13 + kt) * 4 + g) * 16 + l15) * 4);

    float su = 0.f;
#pragma unroll
    for (int kt = 0; kt < 13; ++kt) {
      f32x4 zz = {0.f, 0.f, 0.f, 0.f};
      f32x4 s = mfma16(bkv[kt], aq, zz);  // S^T: col=l15=q, row=g*4+r=k
      us4 pk;
#pragma unroll
      for (int r = 0; r < 4; ++r) {
        float p = __expf(s[r] + bf2f(bv[kt][r]));
        if (kt == 12 && g != 0) p = 0.f;  // k = 192+g*4+r >= 196
        su += p;
        pk[r] = f2bf(p);
      }
      *(us4*)(plw + l15 * PLSTR + kt * 16 + g * 4) = pk;
    }
    su += __shfl_xor(su, 16, 64);
    su += __shfl_xor(su, 32, 64);
    asm volatile("s_waitcnt lgkmcnt(0)" ::: "memory");
    __builtin_amdgcn_sched_barrier(0);
    // PV (P unnormalized)
    f32x4 o0 = {0.f, 0.f, 0.f, 0.f}, o1 = {0.f, 0.f, 0.f, 0.f};
#pragma unroll
    for (int kc = 0; kc < 7; ++kc) {
      int t0 = kc * 32 + g * 8;
      bf16x8 pa = ldfrag(plw + l15 * PLSTR + t0);
      bf16x8 b0 = ldfrag(&Vt[vt_addr(l15, t0)]);
      bf16x8 b1 = ldfrag(&Vt[vt_addr(16 + l15, t0)]);
      o0 = mfma16(pa, b0, o0);
      o1 = mfma16(pa, b1, o1);
    }
    float inv = 1.0f / su;
#pragma unroll
    for (int r = 0; r < 4; ++r) {
      int rw = qt * 16 + g * 4 + r;
      if (rw < 196) {
        size_t rb = ((size_t)win * 196 + rw) * 384 + h * 32;
        aout[rb + l15] = f2bf(o0[r] * inv);
        aout[rb + 16 + l15] = f2bf(o1[r] * inv);
      }
    }
  }
}

// ---------- bf16 GEMM, B^T weights, 128x128 tile, BK=64, templated epilogue ----
// LDS bank-conflict fix (T2 adapted to global_load_lds, rule #21): LDS dest
// stays linear; the STAGING lane pre-swizzles its GLOBAL column granule
// (c8 ^ ((r&7)<<3)), and the fragment READ applies the same XOR. 16-way
// conflict -> 2-way (free).
// MODE 0: +bias, scale q-cols by SCALE -> bf16 out (stride NQKV)
// MODE 1: +bias, window-reverse scatter, x1 = x + val (f32)
// MODE 2: +bias, exact GELU -> bf16 out (stride HIDD)
// MODE 3: +bias, out = auxr + val (f32, stride 384)
template <int MODE, int K>
__global__ __launch_bounds__(256) void k_gemm(const unsigned short* __restrict__ A,
                                              const unsigned short* __restrict__ B,
                                              const float* __restrict__ bias,
                                              const float* __restrict__ auxr,
                                              float* __restrict__ auxw,
                                              unsigned short* __restrict__ outb) {
  __shared__ unsigned short As[128 * 64];
  __shared__ unsigned short Bs[128 * 64];
  const int tid = threadIdx.x;
  const int w = tid >> 6, l = tid & 63;
  const int l15 = l & 15, g = l >> 4;
  const int wm = w >> 1, wn = w & 1;
  // bijective XCD-aware swizzle (m204) on the flat block index
  const int nwg = gridDim.x * gridDim.y;
  const int orig = blockIdx.y * gridDim.x + blockIdx.x;
  const int cq = nwg >> 3, cr = nwg & 7;
  const int xcd = orig & 7, cidx = orig >> 3;
  const int flat = (xcd < cr ? xcd * (cq + 1) : cr * (cq + 1) + (xcd - cr) * cq) + cidx;
  const int bx = flat % gridDim.x, by = flat / gridDim.x;
  const size_t arow0 = (size_t)bx * 128;
  const size_t brow0 = (size_t)by * 128;
  f32x4 acc[4][4] = {};
  for (int ks = 0; ks < K; ks += 64) {
    if (ks) __syncthreads();
#pragma unroll
    for (int it = 0; it < 4; ++it) {
      const int f = it * 256 + tid;
      const int r = f >> 3, c8 = (f & 7) << 3;
      const int c8s = c8 ^ ((r & 7) << 3);  // pre-swizzled SOURCE granule
      const int lb = (it * 256 + w * 64) * 8;  // wave-uniform LDS base (elements)
      async16(A + (arow0 + r) * K + ks + c8s, &As[lb]);
      async16(B + (brow0 + r) * K + ks + c8s, &Bs[lb]);
    }
    __syncthreads();
#pragma unroll
    for (int kk = 0; kk < 2; ++kk) {
      bf16x8 af[4], bfr[4];
#pragma unroll
      for (int i = 0; i < 4; ++i) {
        const int row = wm * 64 + i * 16 + l15;
        af[i] = ldfrag(&As[row * 64 + ((kk * 32 + g * 8) ^ ((row & 7) << 3))]);
      }
#pragma unroll
      for (int j = 0; j < 4; ++j) {
        const int row = wn * 64 + j * 16 + l15;
        bfr[j] = ldfrag(&Bs[row * 64 + ((kk * 32 + g * 8) ^ ((row & 7) << 3))]);
      }
#pragma unroll
      for (int i = 0; i < 4; ++i)
#pragma unroll
        for (int j = 0; j < 4; ++j)
          acc[i][j] = mfma16(af[i], bfr[j], acc[i][j]);
    }
  }
  // epilogue
#pragma unroll
  for (int i = 0; i < 4; ++i) {
#pragma unroll
    for (int j = 0; j < 4; ++j) {
#pragma unroll
      for (int r = 0; r < 4; ++r) {
        const int row = (int)arow0 + wm * 64 + i * 16 + g * 4 + r;
        const int col = (int)brow0 + wn * 64 + j * 16 + l15;
        float v = acc[i][j][r] + bias[col];
        if (MODE == 0) {
          int ch = col % 96;
          float o = (ch < 32) ? v * SCALE : v;  // pre-scale q
          outb[(size_t)row * NQKV + col] = f2bf(o);
        } else if (MODE == 1) {
          if (row < MV) {
            int win = row / 196, t = row - win * 196;
            int b = win / 25, wi = win - b * 25;
            int wr = wi / 5, wc = wi - wr * 5;
            int hh = wr * 14 + t / 14, ww = wc * 14 + (t - (t / 14) * 14);
            if (hh < HW && ww < HW) {
              size_t di = ((size_t)b * 4096 + hh * 64 + ww) * 384 + col;
              auxw[di] = auxr[di] + v;
            }
          }
        } else if (MODE == 2) {
          float gl = 0.5f * v * (1.0f + erff(v * 0.7071067811865475f));
          outb[(size_t)row * HIDD + col] = f2bf(gl);
        } else {
          size_t di = (size_t)row * 384 + col;
          auxw[di] = auxr[di] + v;
        }
      }
    }
  }
}

// ---------- launcher ----------
extern "C" void kernel_launch(void* const* d_in, const int* in_sizes, int n_in,
                              void* d_out, int out_size, void* d_ws, size_t ws_size,
                              hipStream_t stream) {
  const float* x = (const float*)d_in[0];
  const float* ln_attn_w = (const float*)d_in[1];
  const float* ln_attn_b = (const float*)d_in[2];
  const float* qkv_w = (const float*)d_in[3];
  const float* qkv_b = (const float*)d_in[4];
  const float* proj_w = (const float*)d_in[5];
  const float* proj_b = (const float*)d_in[6];
  const float* attn_biases = (const float*)d_in[7];
  const float* conv_w = (const float*)d_in[8];
  const float* bn_w = (const float*)d_in[9];
  const float* bn_b = (const float*)d_in[10];
  const float* bn_mean = (const float*)d_in[11];
  const float* bn_var = (const float*)d_in[12];
  const float* ln_mlp_w = (const float*)d_in[13];
  const float* ln_mlp_b = (const float*)d_in[14];
  const float* fc1_w = (const float*)d_in[15];
  const float* fc1_b = (const float*)d_in[16];
  const float* fc2_w = (const float*)d_in[17];
  const float* fc2_b = (const float*)d_in[18];
  const int* bias_idx = (const int*)d_in[19];

  char* ws = (char*)d_ws;
  size_t off = 0;
  auto alloc = [&](size_t n) {
    void* p = ws + off;
    off = (off + n + 255) & ~(size_t)255;
    return p;
  };
  unsigned short* xn = (unsigned short*)alloc((size_t)MPAD * CDIM * 2);       // reused as xln
  unsigned short* qkv = (unsigned short*)alloc((size_t)MMLP * HIDD * 2);      // reused as h
  unsigned short* attn = (unsigned short*)alloc((size_t)MMLP * CDIM * 4);     // reused as x2 (f32)
  float* x1 = (float*)alloc((size_t)MMLP * CDIM * 4);
  unsigned short* wq = (unsigned short*)alloc((size_t)NQKV * CDIM * 2);
  unsigned short* wp = (unsigned short*)alloc((size_t)CDIM * CDIM * 2);
  unsigned short* w1 = (unsigned short*)alloc((size_t)HIDD * CDIM * 2);
  unsigned short* w2 = (unsigned short*)alloc((size_t)CDIM * HIDD * 2);
  unsigned short* bias_t = (unsigned short*)alloc((size_t)NBIAS * 2);
  unsigned short* hbuf = qkv;
  float* x2 = (float*)attn;
  unsigned short* xln = xn;
  int n_off = in_sizes[7] / HEADS;

  dim3 B256(256);
  k_cvt<<<dim3((NQKV * CDIM + 255) / 256), B256, 0, stream>>>(qkv_w, wq, NQKV * CDIM);
  k_cvt<<<dim3((CDIM * CDIM + 255) / 256), B256, 0, stream>>>(proj_w, wp, CDIM * CDIM);
  k_cvt<<<dim3((HIDD * CDIM + 255) / 256), B256, 0, stream>>>(fc1_w, w1, HIDD * CDIM);
  k_cvt<<<dim3((CDIM * HIDD + 255) / 256), B256, 0, stream>>>(fc2_w, w2, CDIM * HIDD);
  k_bias2<<<dim3((NBIAS + 255) / 256), B256, 0, stream>>>(attn_biases, bias_idx, bias_t, n_off);
  k_ln<1><<<dim3(MPAD / 4), B256, 0, stream>>>(x, ln_attn_w, ln_attn_b, xn);
  k_gemm<0, CDIM><<<dim3(MPAD / 128, NQKV / 128), B256, 0, stream>>>(xn, wq, qkv_b, nullptr, nullptr, qkv);
  k_attn<<<dim3(NWIN * HEADS), B256, 0, stream>>>(qkv, bias_t, attn);
  k_gemm<1, CDIM><<<dim3(MPAD / 128, CDIM / 128), B256, 0, stream>>>(attn, wp, proj_b, x, x1, nullptr);
  k_conv<<<dim3(CBATCH * HW * CDIM / 256), B256, 0, stream>>>(x1, conv_w, bn_w, bn_b, bn_mean, bn_var, x2);
  k_ln<0><<<dim3(MMLP / 4), B256, 0, stream>>>(x2, ln_mlp_w, ln_mlp_b, xln);
  k_gemm<2, CDIM><<<dim3(MMLP / 128, HIDD / 128), B256, 0, stream>>>(xln, w1, fc1_b, nullptr, nullptr, hbuf);
  k_gemm<3, HIDD><<<dim3(MMLP / 128, CDIM / 128), B256, 0, stream>>>(hbuf, w2, fc2_b, x2, (float*)d_out, nullptr);
}